// Round 1
// 1270.009 us; speedup vs baseline: 1.5230x; 1.5230x over previous
//
#include <hip/hip_runtime.h>
#include <math.h>

// Problem: B=16, L=S=1024, H=8, E=64, d=512, Lf=513 (freq rows PADDED to 514)
// Pipeline: transpose(q) -> repack(W) -> conv+GLU -> rfft(q2) ->
//           transpose(k) -> rfft -> transpose(v) -> rfft -> attn(MFMA) -> irfft
// Frequency data is stored bf16-SPLIT: ushort4 (re_hi, im_hi, re_lo, im_lo),
// so the attention GEMMs run on the matrix pipe (mfma_f32_16x16x32_bf16) with
// a 3-product error-compensated split (~2^-17 relative error per product).
// Workspace: 4 regions x 8,421,376 floats = 134,742,016 bytes.

typedef __attribute__((ext_vector_type(8))) short bf16x8;
typedef __attribute__((ext_vector_type(4))) float f32x4;

union U8 { bf16x8 v; unsigned u[4]; };

__device__ __forceinline__ unsigned short f2b(float x) {  // f32 -> bf16 RNE
  unsigned u = __float_as_uint(x);
  return (unsigned short)((u + 0x7FFFu + ((u >> 16) & 1u)) >> 16);
}
__device__ __forceinline__ float b2f(unsigned short h) {
  return __uint_as_float(((unsigned)h) << 16);
}

// ---------------- Stockham FFT core, N=1024, 256 threads ----------------
__device__ __forceinline__ void fft1024(float2* b0, float2* b1,
                                        const float2* twd, int tid) {
  float2* src = b0;
  float2* dst = b1;
#pragma unroll
  for (int st = 0; st < 10; ++st) {
    __syncthreads();
#pragma unroll
    for (int qq = 0; qq < 2; ++qq) {
      int bi = tid + qq * 256;          // butterfly index in [0,512)
      int m = 1 << st;
      int j = bi >> st;
      int jm = j << st;
      float2 c0 = src[bi];
      float2 c1 = src[bi + 512];
      float2 w = twd[jm];
      float2 sum, dif, tw;
      sum.x = c0.x + c1.x; sum.y = c0.y + c1.y;
      dif.x = c0.x - c1.x; dif.y = c0.y - c1.y;
      tw.x = dif.x * w.x - dif.y * w.y;
      tw.y = dif.x * w.y + dif.y * w.x;
      dst[bi + jm] = sum;
      dst[bi + jm + m] = tw;
    }
    float2* tmp = src; src = dst; dst = tmp;
  }
  __syncthreads();
}

// ---------------- transpose: f32 [B][1024][512] -> f32 [B][512][1024] ---
__global__ __launch_bounds__(256) void transpose_kernel(
    const float* __restrict__ in, float* __restrict__ out) {
  __shared__ float tile[32][33];
  int b = blockIdx.z;
  int s0 = blockIdx.x * 32;
  int c0 = blockIdx.y * 32;
  int tx = threadIdx.x & 31;
  int ty = threadIdx.x >> 5;            // 0..7
  const float* ip = in + (size_t)b * (1024 * 512);
  float* op = out + (size_t)b * (1024 * 512);
#pragma unroll
  for (int i = 0; i < 32; i += 8)
    tile[ty + i][tx] = ip[(size_t)(s0 + ty + i) * 512 + c0 + tx];
  __syncthreads();
#pragma unroll
  for (int i = 0; i < 32; i += 8)
    op[(size_t)(c0 + ty + i) * 1024 + s0 + tx] = tile[tx][ty + i];
}

// ------- W repack: [1024 og][512 c][3 t] -> Wp[(c*3+t)][1024 og] --------
__global__ __launch_bounds__(256) void transpose_w_kernel(
    const float* __restrict__ in, float* __restrict__ out) {
  __shared__ float tile[32][33];
  int r0 = blockIdx.x * 32;             // og base (0..1023)
  int c0 = blockIdx.y * 32;             // ct base (0..1535)
  int tx = threadIdx.x & 31;
  int ty = threadIdx.x >> 5;            // 0..7
#pragma unroll
  for (int i = 0; i < 32; i += 8)
    tile[ty + i][tx] = in[(size_t)(r0 + ty + i) * 1536 + c0 + tx];
  __syncthreads();
#pragma unroll
  for (int i = 0; i < 32; i += 8)
    out[(size_t)(c0 + ty + i) * 1024 + r0 + tx] = tile[tx][ty + i];
}

// ------- Conv1d(512->1024,k=3,pad=1) + GLU -> q2 [B][512][L] ------------
__global__ __launch_bounds__(256) void conv_glu_kernel(
    const float* __restrict__ qT,     // [B][512][1024]
    const float* __restrict__ Wp,     // [(c*3+t)*1024 + og] repacked
    const float* __restrict__ bias,   // [1024]
    float* __restrict__ q2t) {        // [B][512][1024]
  __shared__ float Xs[32][66];        // col = l-l0+1; halo at col 0 / 65

  int tid = threadIdx.x;
  int lane = tid & 63;
  int wq = __builtin_amdgcn_readfirstlane(tid >> 6);  // wave 0..3 (uniform)
  int b = blockIdx.z;
  int co0 = blockIdx.y * 32;          // block GLU channel base
  int ca = co0 + wq * 8;              // wave GLU channel base (8 channels)
  int l0 = blockIdx.x * 64;
  int l = l0 + lane;

  const float* xsrc = qT + (size_t)b * (512 * 1024);

  float acc[16];                      // 0..7 = a-rows, 8..15 = g-rows
#pragma unroll
  for (int i = 0; i < 16; ++i) acc[i] = 0.f;

  for (int c0 = 0; c0 < 512; c0 += 32) {
    __syncthreads();
#pragma unroll
    for (int p = 0; p < 2; ++p) {
      int idx = tid + p * 256;
      int r = idx >> 4;               // 0..31
      int c4 = idx & 15;
      float4 x4 = *(const float4*)(xsrc + (size_t)(c0 + r) * 1024 + l0 + c4 * 4);
      Xs[r][1 + c4 * 4] = x4.x;
      Xs[r][2 + c4 * 4] = x4.y;
      Xs[r][3 + c4 * 4] = x4.z;
      Xs[r][4 + c4 * 4] = x4.w;
    }
    if (tid < 64) {                   // halo
      int r = tid >> 1;
      int side = tid & 1;
      int gl = side ? (l0 + 64) : (l0 - 1);
      float hv = 0.f;
      if (gl >= 0 && gl < 1024) hv = xsrc[(size_t)(c0 + r) * 1024 + gl];
      Xs[r][side ? 65 : 0] = hv;
    }
    __syncthreads();

    const float* wrow = Wp + (size_t)c0 * 3 * 1024 + ca;  // uniform
    for (int cc = 0; cc < 32; ++cc) {
      float xl = Xs[cc][lane];        // x[l-1]
      float xc = Xs[cc][lane + 1];    // x[l]
      float xr = Xs[cc][lane + 2];    // x[l+1]
      const float* w0 = wrow + (size_t)(cc * 3) * 1024;
#pragma unroll
      for (int t = 0; t < 3; ++t) {
        const float* wt = w0 + t * 1024;
        float xv = (t == 0) ? xl : ((t == 1) ? xc : xr);
#pragma unroll
        for (int i = 0; i < 8; ++i) {
          acc[i]     += wt[i]       * xv;   // a-rows (og = ca+i)
          acc[8 + i] += wt[512 + i] * xv;   // g-rows (og = 512+ca+i)
        }
      }
    }
  }

  float* orow = q2t + ((size_t)b * 512 + ca) * 1024 + l;
#pragma unroll
  for (int i = 0; i < 8; ++i) {
    float a = acc[i] + bias[ca + i];
    float g = acc[8 + i] + bias[512 + ca + i];
    orow[(size_t)i * 1024] = a / (1.f + __expf(-g));
  }
}

// ------- Forward rfft: f32 row [1024] -> 513 bf16-split complex ---------
// out[x] = (re_hi, im_hi, re_lo, im_lo), row stride 514; col 513 zeroed.
__global__ __launch_bounds__(256) void fft_fwd_kernel(
    const float* __restrict__ in, ushort4* __restrict__ out, float scale) {
  __shared__ float2 sb0[1024];
  __shared__ float2 sb1[1024];
  __shared__ float2 twd[512];
  int tid = threadIdx.x;
  size_t r = blockIdx.x;                // row = (b*8+h)*64 + e
  const float* ip = in + r * 1024;
#pragma unroll
  for (int i = 0; i < 4; ++i) {
    int idx = tid + i * 256;
    sb0[idx] = make_float2(ip[idx], 0.f);
  }
  for (int kk = tid; kk < 512; kk += 256) {
    float ang = -6.283185307179586f * (float)kk * (1.0f / 1024.0f);
    float sn, cs;
    __sincosf(ang, &sn, &cs);
    twd[kk] = make_float2(cs, sn);
  }
  fft1024(sb0, sb1, twd, tid);
  ushort4* op = out + r * 514;          // padded row stride
  for (int x = tid; x < 513; x += 256) {
    float2 v = sb0[x];
    float re = v.x * scale, im = v.y * scale;
    unsigned short rh = f2b(re), ih = f2b(im);
    unsigned short rl = f2b(re - b2f(rh)), il = f2b(im - b2f(ih));
    op[x] = make_ushort4(rh, ih, rl, il);
  }
  if (tid == 0) op[513] = make_ushort4(0, 0, 0, 0);
}

// ---------------- Fused frequency attention (MFMA) -----------------------
// Grid 2176 = 128 bh x 17 x-tiles (32 x each), XCD-swizzled so all 17
// x-tiles of one bh run on one XCD (kf+vf slice stays L2-resident).
// Per 64-y tile: GEMM1 S[32x][64y] (re,im) via mfma 16x16x32 bf16, K=128
// (e re/im interleaved), 3-product hi/lo split; lane-local gate
// (re & im of a score land in the same lane); split scores -> swizzled
// LDS plane; GEMM2 of[32x][64e] (re,im) accumulated in registers over all
// y tiles, K=128 per tile (y re/im interleaved). L1 norm applied at end.
__global__ __launch_bounds__(256) void attn_kernel(
    const ushort4* __restrict__ qf, const ushort4* __restrict__ kf,
    const ushort4* __restrict__ vf, float2* __restrict__ of) {
  __shared__ __align__(16) unsigned char smem[49664];
  ushort4* kv = (ushort4*)smem;                 // [64 e][64 y] swz, 32768 B
  ushort4* qs = (ushort4*)(smem + 32768);       // [64 e][32 x], 16384 B (ph0)
  unsigned char* Shi = smem + 32768;            // [32 x][256 B] swz (after)
  unsigned char* Slo = smem + 40960;            // [32 x][256 B] swz
  float* zred = (float*)(smem + 49152);         // [4 w][32 x]

  int tid = threadIdx.x;
  int w = tid >> 6;                             // wave 0..3
  int lane = tid & 63;
  int grp = lane >> 4;                          // k-group 0..3
  int lid = lane & 15;                          // row/col within frag

  unsigned v0 = blockIdx.x;                     // 0..2175
  unsigned cc = v0 & 7u;                        // XCD
  unsigned jj = v0 >> 3;                        // 0..271
  int bh = (int)(cc + 8u * (jj / 17u));
  int x0 = (int)(jj % 17u) * 32;

  const ushort4* qb = qf + (size_t)bh * (64 * 514);
  const ushort4* kb = kf + (size_t)bh * (64 * 514);
  const ushort4* vb = vf + (size_t)bh * (64 * 514);

  // ---- stage q tile [64 e][32 x] ----
  {
    int x = tid & 31, e0 = tid >> 5;
    int gx = x0 + x;
#pragma unroll
    for (int i = 0; i < 8; ++i) {
      int e = e0 + i * 8;
      ushort4 qv = make_ushort4(0, 0, 0, 0);
      if (gx < 514) qv = qb[(size_t)e * 514 + gx];  // col 513 is zeroed
      qs[e * 32 + x] = qv;
    }
  }
  __syncthreads();

  // ---- A fragments (q) in registers: A[x][k], k = 2e+c, pre-scaled 1/8 ----
  U8 Ah[2][4], Al[2][4];
#pragma unroll
  for (int mt = 0; mt < 2; ++mt)
#pragma unroll
    for (int ks = 0; ks < 4; ++ks)
#pragma unroll
      for (int jp = 0; jp < 4; ++jp) {
        ushort4 qv = qs[(ks * 16 + grp * 4 + jp) * 32 + mt * 16 + lid];
        Ah[mt][ks].u[jp] = (unsigned)qv.x | ((unsigned)qv.y << 16);
        Al[mt][ks].u[jp] = (unsigned)qv.z | ((unsigned)qv.w << 16);
      }

  float zacc[2][4] = {{0.f, 0.f, 0.f, 0.f}, {0.f, 0.f, 0.f, 0.f}};
  f32x4 ore[2] = {{0.f, 0.f, 0.f, 0.f}, {0.f, 0.f, 0.f, 0.f}};
  f32x4 oim[2] = {{0.f, 0.f, 0.f, 0.f}, {0.f, 0.f, 0.f, 0.f}};

  for (int yt = 0; yt < 9; ++yt) {
    int y0 = yt * 64;
    // ---- stage K tile [64 e][64 y], slot = y ^ (e&7) ----
    __syncthreads();
    {
      int yy = (tid & 31) * 2, e0 = tid >> 5;
#pragma unroll
      for (int i = 0; i < 8; ++i) {
        int e = e0 + i * 8;
        uint4 d = make_uint4(0, 0, 0, 0);
        int gy = y0 + yy;
        if (gy < 513) d = *(const uint4*)(kb + (size_t)e * 514 + gy);
        int sw = e & 7;
        *(uint2*)&kv[e * 64 + (yy ^ sw)] = make_uint2(d.x, d.y);
        *(uint2*)&kv[e * 64 + ((yy + 1) ^ sw)] = make_uint2(d.z, d.w);
      }
    }
    __syncthreads();
    // ---- GEMM1: S[x][y] re/im, wave w owns y = y0 + 16w + lid ----
    {
      f32x4 cre[2] = {{0.f, 0.f, 0.f, 0.f}, {0.f, 0.f, 0.f, 0.f}};
      f32x4 cim[2] = {{0.f, 0.f, 0.f, 0.f}, {0.f, 0.f, 0.f, 0.f}};
#pragma unroll
      for (int ks = 0; ks < 4; ++ks) {
        U8 brh, brl, bih, bil;
#pragma unroll
        for (int jp = 0; jp < 4; ++jp) {
          int e = ks * 16 + grp * 4 + jp;
          ushort4 kvv = kv[e * 64 + ((w * 16 + lid) ^ (e & 7))];
          unsigned uh = (unsigned)kvv.x | ((unsigned)kvv.y << 16);  // (kr,ki)
          unsigned ul = (unsigned)kvv.z | ((unsigned)kvv.w << 16);
          brh.u[jp] = uh;                               // (kr, ki)
          brl.u[jp] = ul;
          bih.u[jp] = ((uh >> 16) ^ 0x8000u) | (uh << 16);  // (-ki, kr)
          bil.u[jp] = ((ul >> 16) ^ 0x8000u) | (ul << 16);
        }
#pragma unroll
        for (int mt = 0; mt < 2; ++mt) {
          cre[mt] = __builtin_amdgcn_mfma_f32_16x16x32_bf16(Ah[mt][ks].v, brh.v, cre[mt], 0, 0, 0);
          cre[mt] = __builtin_amdgcn_mfma_f32_16x16x32_bf16(Al[mt][ks].v, brh.v, cre[mt], 0, 0, 0);
          cre[mt] = __builtin_amdgcn_mfma_f32_16x16x32_bf16(Ah[mt][ks].v, brl.v, cre[mt], 0, 0, 0);
          cim[mt] = __builtin_amdgcn_mfma_f32_16x16x32_bf16(Ah[mt][ks].v, bih.v, cim[mt], 0, 0, 0);
          cim[mt] = __builtin_amdgcn_mfma_f32_16x16x32_bf16(Al[mt][ks].v, bih.v, cim[mt], 0, 0, 0);
          cim[mt] = __builtin_amdgcn_mfma_f32_16x16x32_bf16(Ah[mt][ks].v, bil.v, cim[mt], 0, 0, 0);
        }
      }
      // ---- gate + L1 partial + split scores to LDS plane ----
      int ybase4 = 4 * (w * 16 + lid);
#pragma unroll
      for (int mt = 0; mt < 2; ++mt)
#pragma unroll
        for (int r = 0; r < 4; ++r) {
          float sre = cre[mt][r], sim = cim[mt][r];
          float m = sqrtf(sre * sre + sim * sim);
          float f = 1.f + 1.f / (1.f + __expf(-m));
          zacc[mt][r] += m * f;
          float wre = sre * f, wim = sim * f;
          unsigned short hr = f2b(wre), hi2 = f2b(wim);
          unsigned short lr = f2b(wre - b2f(hr)), li = f2b(wim - b2f(hi2));
          int x = mt * 16 + grp * 4 + r;
          int bc = ybase4 ^ ((x & 7) << 4);
          *(unsigned*)(Shi + x * 256 + bc) = (unsigned)hr | ((unsigned)hi2 << 16);
          *(unsigned*)(Slo + x * 256 + bc) = (unsigned)lr | ((unsigned)li << 16);
        }
    }
    __syncthreads();
    // ---- stage V tile ----
    {
      int yy = (tid & 31) * 2, e0 = tid >> 5;
#pragma unroll
      for (int i = 0; i < 8; ++i) {
        int e = e0 + i * 8;
        uint4 d = make_uint4(0, 0, 0, 0);
        int gy = y0 + yy;
        if (gy < 513) d = *(const uint4*)(vb + (size_t)e * 514 + gy);
        int sw = e & 7;
        *(uint2*)&kv[e * 64 + (yy ^ sw)] = make_uint2(d.x, d.y);
        *(uint2*)&kv[e * 64 + ((yy + 1) ^ sw)] = make_uint2(d.z, d.w);
      }
    }
    __syncthreads();
    // ---- GEMM2: of[x][e] re/im += sc * vf, wave w owns e = 16w + lid ----
    {
#pragma unroll
      for (int ks = 0; ks < 4; ++ks) {
        U8 brh, brl, bih, bil;
#pragma unroll
        for (int jp = 0; jp < 4; ++jp) {
          int e = w * 16 + lid;
          int y = ks * 16 + grp * 4 + jp;
          ushort4 vv = kv[e * 64 + (y ^ (e & 7))];
          unsigned uh = (unsigned)vv.x | ((unsigned)vv.y << 16);  // (vr,vi)
          unsigned ul = (unsigned)vv.z | ((unsigned)vv.w << 16);
          brh.u[jp] = uh ^ 0x80000000u;              // (vr, -vi)
          brl.u[jp] = ul ^ 0x80000000u;
          bih.u[jp] = (uh >> 16) | (uh << 16);       // (vi, vr)
          bil.u[jp] = (ul >> 16) | (ul << 16);
        }
#pragma unroll
        for (int mt = 0; mt < 2; ++mt) {
          int x = mt * 16 + lid;
          int bc = (ks * 64 + grp * 16) ^ ((x & 7) << 4);
          U8 a2h, a2l;
          a2h.v = *(const bf16x8*)(Shi + x * 256 + bc);
          a2l.v = *(const bf16x8*)(Slo + x * 256 + bc);
          ore[mt] = __builtin_amdgcn_mfma_f32_16x16x32_bf16(a2h.v, brh.v, ore[mt], 0, 0, 0);
          ore[mt] = __builtin_amdgcn_mfma_f32_16x16x32_bf16(a2l.v, brh.v, ore[mt], 0, 0, 0);
          ore[mt] = __builtin_amdgcn_mfma_f32_16x16x32_bf16(a2h.v, brl.v, ore[mt], 0, 0, 0);
          oim[mt] = __builtin_amdgcn_mfma_f32_16x16x32_bf16(a2h.v, bih.v, oim[mt], 0, 0, 0);
          oim[mt] = __builtin_amdgcn_mfma_f32_16x16x32_bf16(a2l.v, bih.v, oim[mt], 0, 0, 0);
          oim[mt] = __builtin_amdgcn_mfma_f32_16x16x32_bf16(a2h.v, bil.v, oim[mt], 0, 0, 0);
        }
      }
    }
  }

  // ---- Z reduction: per-lane partials -> per-x totals ----
#pragma unroll
  for (int mt = 0; mt < 2; ++mt)
#pragma unroll
    for (int r = 0; r < 4; ++r) {
      float z = zacc[mt][r];
      z += __shfl_xor(z, 1); z += __shfl_xor(z, 2);
      z += __shfl_xor(z, 4); z += __shfl_xor(z, 8);
      zacc[mt][r] = z;
    }
  __syncthreads();                       // all GEMM2 reads of kv done
  if (lid == 0) {
#pragma unroll
    for (int mt = 0; mt < 2; ++mt)
#pragma unroll
      for (int r = 0; r < 4; ++r)
        zred[w * 32 + mt * 16 + grp * 4 + r] = zacc[mt][r];
  }
  __syncthreads();
  // ---- normalize + stage output tile [64 e][32 x] (swz x ^ ((e&7)<<2)) ----
  float2* ov = (float2*)smem;
#pragma unroll
  for (int mt = 0; mt < 2; ++mt)
#pragma unroll
    for (int r = 0; r < 4; ++r) {
      int x = mt * 16 + grp * 4 + r;
      float z = zred[x] + zred[32 + x] + zred[64 + x] + zred[96 + x];
      float inv = 1.f / fmaxf(z, 1e-12f);
      int e = w * 16 + lid;
      ov[e * 32 + (x ^ ((e & 7) << 2))] =
          make_float2(ore[mt][r] * inv, oim[mt][r] * inv);
    }
  __syncthreads();
  // ---- coalesced write: of[(bh*64+e)*513 + x] ----
  {
    float2* ob = of + (size_t)bh * 64 * 513;
#pragma unroll
    for (int i = 0; i < 4; ++i) {
      int e = (tid >> 4) + i * 16;
      int xq = (tid & 15) * 2;
      int sw = (e & 7) << 2;
      float2 a = ov[e * 32 + (xq ^ sw)];
      float2 b2 = ov[e * 32 + ((xq + 1) ^ sw)];
      int gx = x0 + xq;
      if (gx < 513) ob[(size_t)e * 513 + gx] = a;
      if (gx + 1 < 513) ob[(size_t)e * 513 + gx + 1] = b2;
    }
  }
}

// ------- Inverse rfft (ortho), of stride 513 -> f32 out [B,L,H,E] -------
__global__ __launch_bounds__(256) void fft_inv_kernel(
    const float2* __restrict__ in, float* __restrict__ out) {
  __shared__ float2 sb0[1024];
  __shared__ float2 sb1[1024];
  __shared__ float2 twd[512];
  int tid = threadIdx.x;
  size_t r = blockIdx.x;                // (b*8+h)*64 + e
  const float2* ip = in + r * 513;
#pragma unroll
  for (int i = 0; i < 4; ++i) {
    int idx = tid + i * 256;
    float2 v;
    if (idx < 513) {
      v = ip[idx];
    } else {                            // Hermitian mirror
      float2 u = ip[1024 - idx];
      v = make_float2(u.x, -u.y);
    }
    sb0[idx] = v;
  }
  for (int kk = tid; kk < 512; kk += 256) {
    float ang = 6.283185307179586f * (float)kk * (1.0f / 1024.0f);
    float sn, cs;
    __sincosf(ang, &sn, &cs);
    twd[kk] = make_float2(cs, sn);
  }
  fft1024(sb0, sb1, twd, tid);
  int e = (int)(r & 63);
  int h = (int)((r >> 6) & 7);
  size_t b = r >> 9;
  float* op = out + b * (size_t)(1024 * 512) + (size_t)h * 64 + e;
  const float sc = 0.03125f;            // 1/sqrt(1024)
#pragma unroll
  for (int i = 0; i < 4; ++i) {
    int l = tid + i * 256;
    op[(size_t)l * 512] = sb0[l].x * sc;
  }
}

// ---------------- launch ------------------------------------------------
extern "C" void kernel_launch(void* const* d_in, const int* in_sizes, int n_in,
                              void* d_out, int out_size, void* d_ws, size_t ws_size,
                              hipStream_t stream) {
  const float* q = (const float*)d_in[0];
  const float* k = (const float*)d_in[1];
  const float* v = (const float*)d_in[2];
  const float* W = (const float*)d_in[3];
  const float* bias = (const float*)d_in[4];
  float* out = (float*)d_out;

  // Workspace map (float offsets), regions of 8,421,376 floats each:
  //   A   [0)         reused: q2t -> kT -> vT -> of
  //   QFR [8421376)   reused: qTd (transposed q) -> qf (bf16-split, 514 u4/row)
  //   vf  [16842752)  reused: Wp (repacked W) -> vf
  //   kf  [25264128)
  float* wsf = (float*)d_ws;
  float*   A   = wsf;
  float*   qTd = wsf + 8421376;
  ushort4* qf  = (ushort4*)(wsf + 8421376);
  float*   Wp  = wsf + 16842752;
  ushort4* vf  = (ushort4*)(wsf + 16842752);
  ushort4* kf  = (ushort4*)(wsf + 25264128);
  float2*  of  = (float2*)wsf;          // of stride 513, fits in A region

  transpose_kernel<<<dim3(32, 16, 16), 256, 0, stream>>>(q, qTd);
  transpose_w_kernel<<<dim3(32, 48), 256, 0, stream>>>(W, Wp);
  conv_glu_kernel<<<dim3(16, 16, 16), 256, 0, stream>>>(qTd, Wp, bias, A);
  fft_fwd_kernel<<<dim3(8192), 256, 0, stream>>>(A, qf, 0.03125f * 0.125f);
  transpose_kernel<<<dim3(32, 16, 16), 256, 0, stream>>>(k, A);
  fft_fwd_kernel<<<dim3(8192), 256, 0, stream>>>(A, kf, 0.03125f);
  transpose_kernel<<<dim3(32, 16, 16), 256, 0, stream>>>(v, A);
  fft_fwd_kernel<<<dim3(8192), 256, 0, stream>>>(A, vf, 0.03125f);
  attn_kernel<<<dim3(2176), 256, 0, stream>>>(qf, kf, vf, of);
  fft_inv_kernel<<<dim3(8192), 256, 0, stream>>>(of, out);
}

// Round 3
// 834.341 us; speedup vs baseline: 2.3182x; 1.5222x over previous
//
#include <hip/hip_runtime.h>
#include <math.h>

// Problem: B=16, L=S=1024, H=8, E=64, d=512, Lf=513 (freq rows PADDED to 514)
// Pipeline: split-transpose(q) -> split-repack(W) -> conv+GLU (MFMA) ->
//           rfft(q2) -> transpose(k) -> rfft -> transpose(v) -> rfft ->
//           attn(MFMA) -> irfft
// All matmul-shaped compute (conv GEMM + both attention GEMMs) runs on
// mfma_f32_16x16x32_bf16 with a 3-product error-compensated hi/lo split
// (~2^-17 relative error per product; below the f32-FFT error floor).
// Workspace: 4 regions x 8,421,376 floats = 134,742,016 bytes.

typedef __attribute__((ext_vector_type(8))) short bf16x8;
typedef __attribute__((ext_vector_type(4))) float f32x4;

union U8 { bf16x8 v; unsigned u[4]; };

__device__ __forceinline__ unsigned short f2b(float x) {  // f32 -> bf16 RNE
  unsigned u = __float_as_uint(x);
  return (unsigned short)((u + 0x7FFFu + ((u >> 16) & 1u)) >> 16);
}
__device__ __forceinline__ float b2f(unsigned short h) {
  return __uint_as_float(((unsigned)h) << 16);
}

// ---------------- Stockham FFT core, N=1024, 256 threads ----------------
__device__ __forceinline__ void fft1024(float2* b0, float2* b1,
                                        const float2* twd, int tid) {
  float2* src = b0;
  float2* dst = b1;
#pragma unroll
  for (int st = 0; st < 10; ++st) {
    __syncthreads();
#pragma unroll
    for (int qq = 0; qq < 2; ++qq) {
      int bi = tid + qq * 256;          // butterfly index in [0,512)
      int m = 1 << st;
      int j = bi >> st;
      int jm = j << st;
      float2 c0 = src[bi];
      float2 c1 = src[bi + 512];
      float2 w = twd[jm];
      float2 sum, dif, tw;
      sum.x = c0.x + c1.x; sum.y = c0.y + c1.y;
      dif.x = c0.x - c1.x; dif.y = c0.y - c1.y;
      tw.x = dif.x * w.x - dif.y * w.y;
      tw.y = dif.x * w.y + dif.y * w.x;
      dst[bi + jm] = sum;
      dst[bi + jm + m] = tw;
    }
    float2* tmp = src; src = dst; dst = tmp;
  }
  __syncthreads();
}

// ---------------- transpose: f32 [B][1024][512] -> f32 [B][512][1024] ---
// (still used for k and v feeding the forward FFT)
__global__ __launch_bounds__(256) void transpose_kernel(
    const float* __restrict__ in, float* __restrict__ out) {
  __shared__ float tile[32][33];
  int b = blockIdx.z;
  int s0 = blockIdx.x * 32;
  int c0 = blockIdx.y * 32;
  int tx = threadIdx.x & 31;
  int ty = threadIdx.x >> 5;            // 0..7
  const float* ip = in + (size_t)b * (1024 * 512);
  float* op = out + (size_t)b * (1024 * 512);
#pragma unroll
  for (int i = 0; i < 32; i += 8)
    tile[ty + i][tx] = ip[(size_t)(s0 + ty + i) * 512 + c0 + tx];
  __syncthreads();
#pragma unroll
  for (int i = 0; i < 32; i += 8)
    op[(size_t)(c0 + ty + i) * 1024 + s0 + tx] = tile[tx][ty + i];
}

// ------- q split-transpose: f32 [B][1024 l][512 c] -> bf16-split pair ---
// XPhi/XPlo [B][1024 l][256 p] uint: pair p packs channels (2p, 2p+1):
// low 16 bits = c=2p, high = c=2p+1. hi plane = bf16(x), lo = bf16(x-hi).
__global__ __launch_bounds__(256) void transpose_q_split(
    const float* __restrict__ in, unsigned* __restrict__ XPhi,
    unsigned* __restrict__ XPlo) {
  __shared__ float tile[32][33];
  int b = blockIdx.z;
  int l0 = blockIdx.x * 32;
  int c0 = blockIdx.y * 32;
  int tx = threadIdx.x & 31;
  int ty = threadIdx.x >> 5;            // 0..7
  const float* ip = in + (size_t)b * (1024 * 512);
#pragma unroll
  for (int i = 0; i < 32; i += 8)
    tile[ty + i][tx] = ip[(size_t)(l0 + ty + i) * 512 + c0 + tx];
  __syncthreads();
  int p = threadIdx.x & 15;
  int lb = threadIdx.x >> 4;            // 0..15
#pragma unroll
  for (int i = 0; i < 2; ++i) {
    int ll = lb + i * 16;
    float v0 = tile[ll][2 * p];
    float v1 = tile[ll][2 * p + 1];
    unsigned short h0 = f2b(v0), h1 = f2b(v1);
    unsigned short q0 = f2b(v0 - b2f(h0)), q1 = f2b(v1 - b2f(h1));
    size_t o = ((size_t)b * 1024 + l0 + ll) * 256 + (c0 >> 1) + p;
    XPhi[o] = (unsigned)h0 | ((unsigned)h1 << 16);
    XPlo[o] = (unsigned)q0 | ((unsigned)q1 << 16);
  }
}

// ------- W split-repack: [1024 og][512 c][3 t] f32 ->
//         Wsp[(p*3+t)*1024 + og] uint2 {hi_pair, lo_pair}, p = c/2 -------
__global__ __launch_bounds__(256) void transpose_w_split(
    const float* __restrict__ Win, uint2* __restrict__ Wsp) {
  __shared__ float tile[32][49];        // [og][48 ct = 8 pairs x 3 t x 2]
  int og0 = blockIdx.x * 32;
  int ct0 = blockIdx.y * 48;
  int tid = threadIdx.x;
#pragma unroll
  for (int i = 0; i < 6; ++i) {
    int flat = tid + i * 256;
    int og = flat / 48, ct = flat % 48;
    tile[og][ct] = Win[(size_t)(og0 + og) * 1536 + ct0 + ct];
  }
  __syncthreads();
  int ogl = tid & 31;
  int s = tid >> 5;                     // 0..7
#pragma unroll
  for (int i = 0; i < 3; ++i) {
    int pt = s + i * 8;                 // 0..23
    int pl = pt / 3, t = pt % 3;
    float v0 = tile[ogl][pl * 6 + t];       // c = 2*(ct0/6 + pl)
    float v1 = tile[ogl][pl * 6 + 3 + t];   // c+1
    unsigned short h0 = f2b(v0), h1 = f2b(v1);
    unsigned short q0 = f2b(v0 - b2f(h0)), q1 = f2b(v1 - b2f(h1));
    Wsp[((size_t)(ct0 / 6 + pl) * 3 + t) * 1024 + og0 + ogl] =
        make_uint2((unsigned)h0 | ((unsigned)h1 << 16),
                   (unsigned)q0 | ((unsigned)q1 << 16));
  }
}

// ------- Conv1d(512->1024,k=3,pad=1) + GLU via MFMA -> q2 [B][512][L] ---
// GEMM: C[og][l] = sum_{c,t} W[og][c][t] * X[c][l+t-1]; M=64 og (32 GLU ch,
// a-rows + g-rows), N=256 l (4 waves x 64), K=512c x 3t. 3-product hi/lo
// split. W tile in LDS (stride-18 rows, b64 frag reads, ~4-way max alias);
// X B-fragments loaded directly from L2 (predicated dwordx4, pad via
// bounds). Grid 1024 = 16 b x 16 ca x 4 l, XCD-swizzled: each XCD owns 2
// batches -> X[b] (2 MB) + W slice stay L2-resident.
__global__ __launch_bounds__(256, 2) void conv_glu_mfma(
    const unsigned* __restrict__ XPhi, const unsigned* __restrict__ XPlo,
    const uint2* __restrict__ Wsp, const float* __restrict__ bias,
    float* __restrict__ q2t) {
  __shared__ unsigned Whi[3 * 64 * 18];
  __shared__ unsigned Wlo[3 * 64 * 18];

  int tid = threadIdx.x;
  int w = tid >> 6;                     // wave 0..3
  int lane = tid & 63;
  int grp = lane >> 4;                  // k-group 0..3
  int lid = lane & 15;

  unsigned v0 = blockIdx.x;             // 0..1023
  int xcd = (int)(v0 & 7u);
  int j = (int)(v0 >> 3);               // 0..127
  int b = xcd * 2 + (j >> 6);
  int rem = j & 63;
  int ca = (rem >> 2) * 32;             // GLU channel base
  int l0 = (rem & 3) * 256;             // l base

  const unsigned* xh = XPhi + (size_t)b * 1024 * 256;
  const unsigned* xl = XPlo + (size_t)b * 1024 * 256;

  f32x4 acc[4][4];
#pragma unroll
  for (int mi = 0; mi < 4; ++mi)
#pragma unroll
    for (int ni = 0; ni < 4; ++ni) acc[mi][ni] = {0.f, 0.f, 0.f, 0.f};

  for (int c0 = 0; c0 < 512; c0 += 32) {
    __syncthreads();
    // stage W tile: 16 pairs x 3 t x 64 og (a-rows 0..31, g-rows 32..63)
#pragma unroll
    for (int i = 0; i < 12; ++i) {
      int flat = tid + i * 256;
      int ogi = flat & 63;
      int r = flat >> 6;                // 0..47
      int t = r % 3, p = r / 3;
      int og = (ogi < 32) ? (ca + ogi) : (480 + ca + ogi);
      uint2 g = Wsp[((size_t)((c0 >> 1) + p) * 3 + t) * 1024 + og];
      Whi[(t * 64 + ogi) * 18 + p] = g.x;
      Wlo[(t * 64 + ogi) * 18 + p] = g.y;
    }
    __syncthreads();

#pragma unroll
    for (int t = 0; t < 3; ++t) {
      U8 Ah[4], Al[4];
#pragma unroll
      for (int mi = 0; mi < 4; ++mi) {
        int base = (t * 64 + mi * 16 + lid) * 18 + 4 * grp;
        uint2 h0 = *(const uint2*)&Whi[base];
        uint2 h1 = *(const uint2*)&Whi[base + 2];
        uint2 g0 = *(const uint2*)&Wlo[base];
        uint2 g1 = *(const uint2*)&Wlo[base + 2];
        Ah[mi].u[0] = h0.x; Ah[mi].u[1] = h0.y;
        Ah[mi].u[2] = h1.x; Ah[mi].u[3] = h1.y;
        Al[mi].u[0] = g0.x; Al[mi].u[1] = g0.y;
        Al[mi].u[2] = g1.x; Al[mi].u[3] = g1.y;
      }
      U8 Bh[4], Bl[4];
#pragma unroll
      for (int ni = 0; ni < 4; ++ni) {
        unsigned gl = (unsigned)(l0 + w * 64 + ni * 16 + lid + t - 1);
        uint4 dh = make_uint4(0, 0, 0, 0), dl = make_uint4(0, 0, 0, 0);
        if (gl < 1024u) {
          // pair base = (c0>>1) for this K-tile + 4*grp within the tile
          size_t off = (size_t)gl * 256 + (c0 >> 1) + 4 * grp;
          dh = *(const uint4*)(xh + off);
          dl = *(const uint4*)(xl + off);
        }
        Bh[ni].u[0] = dh.x; Bh[ni].u[1] = dh.y;
        Bh[ni].u[2] = dh.z; Bh[ni].u[3] = dh.w;
        Bl[ni].u[0] = dl.x; Bl[ni].u[1] = dl.y;
        Bl[ni].u[2] = dl.z; Bl[ni].u[3] = dl.w;
      }
#pragma unroll
      for (int mi = 0; mi < 4; ++mi)
#pragma unroll
        for (int ni = 0; ni < 4; ++ni) {
          acc[mi][ni] = __builtin_amdgcn_mfma_f32_16x16x32_bf16(
              Ah[mi].v, Bl[ni].v, acc[mi][ni], 0, 0, 0);
          acc[mi][ni] = __builtin_amdgcn_mfma_f32_16x16x32_bf16(
              Al[mi].v, Bh[ni].v, acc[mi][ni], 0, 0, 0);
          acc[mi][ni] = __builtin_amdgcn_mfma_f32_16x16x32_bf16(
              Ah[mi].v, Bh[ni].v, acc[mi][ni], 0, 0, 0);
        }
    }
  }

  // epilogue: GLU is lane-local (a at mi, g at mi+2, same lane)
#pragma unroll
  for (int mi = 0; mi < 2; ++mi)
#pragma unroll
    for (int rr = 0; rr < 4; ++rr) {
      int row = mi * 16 + grp * 4 + rr;     // 0..31
      float ba = bias[ca + row];
      float bg = bias[512 + ca + row];
      float* orow =
          q2t + ((size_t)b * 512 + ca + row) * 1024 + l0 + w * 64 + lid;
#pragma unroll
      for (int ni = 0; ni < 4; ++ni) {
        float a = acc[mi][ni][rr] + ba;
        float g = acc[mi + 2][ni][rr] + bg;
        orow[ni * 16] = a / (1.f + __expf(-g));
      }
    }
}

// ------- Forward rfft: f32 row [1024] -> 513 bf16-split complex ---------
// out[x] = (re_hi, im_hi, re_lo, im_lo), row stride 514; col 513 zeroed.
__global__ __launch_bounds__(256) void fft_fwd_kernel(
    const float* __restrict__ in, ushort4* __restrict__ out, float scale) {
  __shared__ float2 sb0[1024];
  __shared__ float2 sb1[1024];
  __shared__ float2 twd[512];
  int tid = threadIdx.x;
  size_t r = blockIdx.x;                // row = (b*8+h)*64 + e
  const float* ip = in + r * 1024;
#pragma unroll
  for (int i = 0; i < 4; ++i) {
    int idx = tid + i * 256;
    sb0[idx] = make_float2(ip[idx], 0.f);
  }
  for (int kk = tid; kk < 512; kk += 256) {
    float ang = -6.283185307179586f * (float)kk * (1.0f / 1024.0f);
    float sn, cs;
    __sincosf(ang, &sn, &cs);
    twd[kk] = make_float2(cs, sn);
  }
  fft1024(sb0, sb1, twd, tid);
  ushort4* op = out + r * 514;          // padded row stride
  for (int x = tid; x < 513; x += 256) {
    float2 v = sb0[x];
    float re = v.x * scale, im = v.y * scale;
    unsigned short rh = f2b(re), ih = f2b(im);
    unsigned short rl = f2b(re - b2f(rh)), il = f2b(im - b2f(ih));
    op[x] = make_ushort4(rh, ih, rl, il);
  }
  if (tid == 0) op[513] = make_ushort4(0, 0, 0, 0);
}

// ---------------- Fused frequency attention (MFMA) -----------------------
// Grid 2176 = 128 bh x 17 x-tiles (32 x each), XCD-swizzled so all 17
// x-tiles of one bh run on one XCD (kf+vf slice stays L2-resident).
__global__ __launch_bounds__(256) void attn_kernel(
    const ushort4* __restrict__ qf, const ushort4* __restrict__ kf,
    const ushort4* __restrict__ vf, float2* __restrict__ of) {
  __shared__ __align__(16) unsigned char smem[49664];
  ushort4* kv = (ushort4*)smem;                 // [64 e][64 y] swz, 32768 B
  ushort4* qs = (ushort4*)(smem + 32768);       // [64 e][32 x], 16384 B (ph0)
  unsigned char* Shi = smem + 32768;            // [32 x][256 B] swz (after)
  unsigned char* Slo = smem + 40960;            // [32 x][256 B] swz
  float* zred = (float*)(smem + 49152);         // [4 w][32 x]

  int tid = threadIdx.x;
  int w = tid >> 6;                             // wave 0..3
  int lane = tid & 63;
  int grp = lane >> 4;                          // k-group 0..3
  int lid = lane & 15;                          // row/col within frag

  unsigned v0 = blockIdx.x;                     // 0..2175
  unsigned cc = v0 & 7u;                        // XCD
  unsigned jj = v0 >> 3;                        // 0..271
  int bh = (int)(cc + 8u * (jj / 17u));
  int x0 = (int)(jj % 17u) * 32;

  const ushort4* qb = qf + (size_t)bh * (64 * 514);
  const ushort4* kb = kf + (size_t)bh * (64 * 514);
  const ushort4* vb = vf + (size_t)bh * (64 * 514);

  // ---- stage q tile [64 e][32 x] ----
  {
    int x = tid & 31, e0 = tid >> 5;
    int gx = x0 + x;
#pragma unroll
    for (int i = 0; i < 8; ++i) {
      int e = e0 + i * 8;
      ushort4 qv = make_ushort4(0, 0, 0, 0);
      if (gx < 514) qv = qb[(size_t)e * 514 + gx];  // col 513 is zeroed
      qs[e * 32 + x] = qv;
    }
  }
  __syncthreads();

  // ---- A fragments (q) in registers: A[x][k], k = 2e+c, pre-scaled 1/8 ----
  U8 Ah[2][4], Al[2][4];
#pragma unroll
  for (int mt = 0; mt < 2; ++mt)
#pragma unroll
    for (int ks = 0; ks < 4; ++ks)
#pragma unroll
      for (int jp = 0; jp < 4; ++jp) {
        ushort4 qv = qs[(ks * 16 + grp * 4 + jp) * 32 + mt * 16 + lid];
        Ah[mt][ks].u[jp] = (unsigned)qv.x | ((unsigned)qv.y << 16);
        Al[mt][ks].u[jp] = (unsigned)qv.z | ((unsigned)qv.w << 16);
      }

  float zacc[2][4] = {{0.f, 0.f, 0.f, 0.f}, {0.f, 0.f, 0.f, 0.f}};
  f32x4 ore[2] = {{0.f, 0.f, 0.f, 0.f}, {0.f, 0.f, 0.f, 0.f}};
  f32x4 oim[2] = {{0.f, 0.f, 0.f, 0.f}, {0.f, 0.f, 0.f, 0.f}};

  for (int yt = 0; yt < 9; ++yt) {
    int y0 = yt * 64;
    // ---- stage K tile [64 e][64 y], slot = y ^ (e&7) ----
    __syncthreads();
    {
      int yy = (tid & 31) * 2, e0 = tid >> 5;
#pragma unroll
      for (int i = 0; i < 8; ++i) {
        int e = e0 + i * 8;
        uint4 d = make_uint4(0, 0, 0, 0);
        int gy = y0 + yy;
        if (gy < 513) d = *(const uint4*)(kb + (size_t)e * 514 + gy);
        int sw = e & 7;
        *(uint2*)&kv[e * 64 + (yy ^ sw)] = make_uint2(d.x, d.y);
        *(uint2*)&kv[e * 64 + ((yy + 1) ^ sw)] = make_uint2(d.z, d.w);
      }
    }
    __syncthreads();
    // ---- GEMM1: S[x][y] re/im, wave w owns y = y0 + 16w + lid ----
    {
      f32x4 cre[2] = {{0.f, 0.f, 0.f, 0.f}, {0.f, 0.f, 0.f, 0.f}};
      f32x4 cim[2] = {{0.f, 0.f, 0.f, 0.f}, {0.f, 0.f, 0.f, 0.f}};
#pragma unroll
      for (int ks = 0; ks < 4; ++ks) {
        U8 brh, brl, bih, bil;
#pragma unroll
        for (int jp = 0; jp < 4; ++jp) {
          int e = ks * 16 + grp * 4 + jp;
          ushort4 kvv = kv[e * 64 + ((w * 16 + lid) ^ (e & 7))];
          unsigned uh = (unsigned)kvv.x | ((unsigned)kvv.y << 16);  // (kr,ki)
          unsigned ul = (unsigned)kvv.z | ((unsigned)kvv.w << 16);
          brh.u[jp] = uh;                               // (kr, ki)
          brl.u[jp] = ul;
          bih.u[jp] = ((uh >> 16) ^ 0x8000u) | (uh << 16);  // (-ki, kr)
          bil.u[jp] = ((ul >> 16) ^ 0x8000u) | (ul << 16);
        }
#pragma unroll
        for (int mt = 0; mt < 2; ++mt) {
          cre[mt] = __builtin_amdgcn_mfma_f32_16x16x32_bf16(Ah[mt][ks].v, brh.v, cre[mt], 0, 0, 0);
          cre[mt] = __builtin_amdgcn_mfma_f32_16x16x32_bf16(Al[mt][ks].v, brh.v, cre[mt], 0, 0, 0);
          cre[mt] = __builtin_amdgcn_mfma_f32_16x16x32_bf16(Ah[mt][ks].v, brl.v, cre[mt], 0, 0, 0);
          cim[mt] = __builtin_amdgcn_mfma_f32_16x16x32_bf16(Ah[mt][ks].v, bih.v, cim[mt], 0, 0, 0);
          cim[mt] = __builtin_amdgcn_mfma_f32_16x16x32_bf16(Al[mt][ks].v, bih.v, cim[mt], 0, 0, 0);
          cim[mt] = __builtin_amdgcn_mfma_f32_16x16x32_bf16(Ah[mt][ks].v, bil.v, cim[mt], 0, 0, 0);
        }
      }
      // ---- gate + L1 partial + split scores to LDS plane ----
      int ybase4 = 4 * (w * 16 + lid);
#pragma unroll
      for (int mt = 0; mt < 2; ++mt)
#pragma unroll
        for (int r = 0; r < 4; ++r) {
          float sre = cre[mt][r], sim = cim[mt][r];
          float m = sqrtf(sre * sre + sim * sim);
          float f = 1.f + 1.f / (1.f + __expf(-m));
          zacc[mt][r] += m * f;
          float wre = sre * f, wim = sim * f;
          unsigned short hr = f2b(wre), hi2 = f2b(wim);
          unsigned short lr = f2b(wre - b2f(hr)), li = f2b(wim - b2f(hi2));
          int x = mt * 16 + grp * 4 + r;
          int bc = ybase4 ^ ((x & 7) << 4);
          *(unsigned*)(Shi + x * 256 + bc) = (unsigned)hr | ((unsigned)hi2 << 16);
          *(unsigned*)(Slo + x * 256 + bc) = (unsigned)lr | ((unsigned)li << 16);
        }
    }
    __syncthreads();
    // ---- stage V tile ----
    {
      int yy = (tid & 31) * 2, e0 = tid >> 5;
#pragma unroll
      for (int i = 0; i < 8; ++i) {
        int e = e0 + i * 8;
        uint4 d = make_uint4(0, 0, 0, 0);
        int gy = y0 + yy;
        if (gy < 513) d = *(const uint4*)(vb + (size_t)e * 514 + gy);
        int sw = e & 7;
        *(uint2*)&kv[e * 64 + (yy ^ sw)] = make_uint2(d.x, d.y);
        *(uint2*)&kv[e * 64 + ((yy + 1) ^ sw)] = make_uint2(d.z, d.w);
      }
    }
    __syncthreads();
    // ---- GEMM2: of[x][e] re/im += sc * vf, wave w owns e = 16w + lid ----
    {
#pragma unroll
      for (int ks = 0; ks < 4; ++ks) {
        U8 brh, brl, bih, bil;
#pragma unroll
        for (int jp = 0; jp < 4; ++jp) {
          int e = w * 16 + lid;
          int y = ks * 16 + grp * 4 + jp;
          ushort4 vv = kv[e * 64 + (y ^ (e & 7))];
          unsigned uh = (unsigned)vv.x | ((unsigned)vv.y << 16);  // (vr,vi)
          unsigned ul = (unsigned)vv.z | ((unsigned)vv.w << 16);
          brh.u[jp] = uh ^ 0x80000000u;              // (vr, -vi)
          brl.u[jp] = ul ^ 0x80000000u;
          bih.u[jp] = (uh >> 16) | (uh << 16);       // (vi, vr)
          bil.u[jp] = (ul >> 16) | (ul << 16);
        }
#pragma unroll
        for (int mt = 0; mt < 2; ++mt) {
          int x = mt * 16 + lid;
          int bc = (ks * 64 + grp * 16) ^ ((x & 7) << 4);
          U8 a2h, a2l;
          a2h.v = *(const bf16x8*)(Shi + x * 256 + bc);
          a2l.v = *(const bf16x8*)(Slo + x * 256 + bc);
          ore[mt] = __builtin_amdgcn_mfma_f32_16x16x32_bf16(a2h.v, brh.v, ore[mt], 0, 0, 0);
          ore[mt] = __builtin_amdgcn_mfma_f32_16x16x32_bf16(a2l.v, brh.v, ore[mt], 0, 0, 0);
          ore[mt] = __builtin_amdgcn_mfma_f32_16x16x32_bf16(a2h.v, brl.v, ore[mt], 0, 0, 0);
          oim[mt] = __builtin_amdgcn_mfma_f32_16x16x32_bf16(a2h.v, bih.v, oim[mt], 0, 0, 0);
          oim[mt] = __builtin_amdgcn_mfma_f32_16x16x32_bf16(a2l.v, bih.v, oim[mt], 0, 0, 0);
          oim[mt] = __builtin_amdgcn_mfma_f32_16x16x32_bf16(a2h.v, bil.v, oim[mt], 0, 0, 0);
        }
      }
    }
  }

  // ---- Z reduction: per-lane partials -> per-x totals ----
#pragma unroll
  for (int mt = 0; mt < 2; ++mt)
#pragma unroll
    for (int r = 0; r < 4; ++r) {
      float z = zacc[mt][r];
      z += __shfl_xor(z, 1); z += __shfl_xor(z, 2);
      z += __shfl_xor(z, 4); z += __shfl_xor(z, 8);
      zacc[mt][r] = z;
    }
  __syncthreads();                       // all GEMM2 reads of kv done
  if (lid == 0) {
#pragma unroll
    for (int mt = 0; mt < 2; ++mt)
#pragma unroll
      for (int r = 0; r < 4; ++r)
        zred[w * 32 + mt * 16 + grp * 4 + r] = zacc[mt][r];
  }
  __syncthreads();
  // ---- normalize + stage output tile [64 e][32 x] (swz x ^ ((e&7)<<2)) ----
  float2* ov = (float2*)smem;
#pragma unroll
  for (int mt = 0; mt < 2; ++mt)
#pragma unroll
    for (int r = 0; r < 4; ++r) {
      int x = mt * 16 + grp * 4 + r;
      float z = zred[x] + zred[32 + x] + zred[64 + x] + zred[96 + x];
      float inv = 1.f / fmaxf(z, 1e-12f);
      int e = w * 16 + lid;
      ov[e * 32 + (x ^ ((e & 7) << 2))] =
          make_float2(ore[mt][r] * inv, oim[mt][r] * inv);
    }
  __syncthreads();
  // ---- coalesced write: of[(bh*64+e)*513 + x] ----
  {
    float2* ob = of + (size_t)bh * 64 * 513;
#pragma unroll
    for (int i = 0; i < 4; ++i) {
      int e = (tid >> 4) + i * 16;
      int xq = (tid & 15) * 2;
      int sw = (e & 7) << 2;
      float2 a = ov[e * 32 + (xq ^ sw)];
      float2 b2 = ov[e * 32 + ((xq + 1) ^ sw)];
      int gx = x0 + xq;
      if (gx < 513) ob[(size_t)e * 513 + gx] = a;
      if (gx + 1 < 513) ob[(size_t)e * 513 + gx + 1] = b2;
    }
  }
}

// ------- Inverse rfft (ortho), of stride 513 -> f32 out [B,L,H,E] -------
__global__ __launch_bounds__(256) void fft_inv_kernel(
    const float2* __restrict__ in, float* __restrict__ out) {
  __shared__ float2 sb0[1024];
  __shared__ float2 sb1[1024];
  __shared__ float2 twd[512];
  int tid = threadIdx.x;
  size_t r = blockIdx.x;                // (b*8+h)*64 + e
  const float2* ip = in + r * 513;
#pragma unroll
  for (int i = 0; i < 4; ++i) {
    int idx = tid + i * 256;
    float2 v;
    if (idx < 513) {
      v = ip[idx];
    } else {                            // Hermitian mirror
      float2 u = ip[1024 - idx];
      v = make_float2(u.x, -u.y);
    }
    sb0[idx] = v;
  }
  for (int kk = tid; kk < 512; kk += 256) {
    float ang = 6.283185307179586f * (float)kk * (1.0f / 1024.0f);
    float sn, cs;
    __sincosf(ang, &sn, &cs);
    twd[kk] = make_float2(cs, sn);
  }
  fft1024(sb0, sb1, twd, tid);
  int e = (int)(r & 63);
  int h = (int)((r >> 6) & 7);
  size_t b = r >> 9;
  float* op = out + b * (size_t)(1024 * 512) + (size_t)h * 64 + e;
  const float sc = 0.03125f;            // 1/sqrt(1024)
#pragma unroll
  for (int i = 0; i < 4; ++i) {
    int l = tid + i * 256;
    op[(size_t)l * 512] = sb0[l].x * sc;
  }
}

// ---------------- launch ------------------------------------------------
extern "C" void kernel_launch(void* const* d_in, const int* in_sizes, int n_in,
                              void* d_out, int out_size, void* d_ws, size_t ws_size,
                              hipStream_t stream) {
  const float* q = (const float*)d_in[0];
  const float* k = (const float*)d_in[1];
  const float* v = (const float*)d_in[2];
  const float* W = (const float*)d_in[3];
  const float* bias = (const float*)d_in[4];
  float* out = (float*)d_out;

  // Workspace map (float offsets), regions of 8,421,376 floats each:
  //   A   [0)         reused: q2t -> kT -> vT -> of
  //   QFR [8421376)   reused: XPhi+XPlo (split q) -> qf (bf16-split freq)
  //   vf  [16842752)  reused: Wsp (split W) -> vf
  //   kf  [25264128)
  float* wsf = (float*)d_ws;
  float*    A    = wsf;
  unsigned* XPhi = (unsigned*)(wsf + 8421376);
  unsigned* XPlo = XPhi + (size_t)16 * 1024 * 256;   // +16 MB
  ushort4*  qf   = (ushort4*)(wsf + 8421376);
  uint2*    Wsp  = (uint2*)(wsf + 16842752);
  ushort4*  vf   = (ushort4*)(wsf + 16842752);
  ushort4*  kf   = (ushort4*)(wsf + 25264128);
  float2*   of   = (float2*)wsf;        // of stride 513, fits in A region

  transpose_q_split<<<dim3(32, 16, 16), 256, 0, stream>>>(q, XPhi, XPlo);
  transpose_w_split<<<dim3(32, 32), 256, 0, stream>>>(W, Wsp);
  conv_glu_mfma<<<dim3(1024), 256, 0, stream>>>(XPhi, XPlo, Wsp, bias, A);
  fft_fwd_kernel<<<dim3(8192), 256, 0, stream>>>(A, qf, 0.03125f * 0.125f);
  transpose_kernel<<<dim3(32, 16, 16), 256, 0, stream>>>(k, A);
  fft_fwd_kernel<<<dim3(8192), 256, 0, stream>>>(A, kf, 0.03125f);
  transpose_kernel<<<dim3(32, 16, 16), 256, 0, stream>>>(v, A);
  fft_fwd_kernel<<<dim3(8192), 256, 0, stream>>>(A, vf, 0.03125f);
  attn_kernel<<<dim3(2176), 256, 0, stream>>>(qf, kf, vf, of);
  fft_inv_kernel<<<dim3(8192), 256, 0, stream>>>(of, out);
}

// Round 4
// 774.292 us; speedup vs baseline: 2.4980x; 1.0776x over previous
//
#include <hip/hip_runtime.h>
#include <math.h>

// Problem: B=16, L=S=1024, H=8, E=64, d=512, Lf=513 (freq rows PADDED to 514)
// Pipeline: split-transpose(q) -> split-repack(W) -> conv+GLU (MFMA) ->
//           rfft(q2) -> transpose(k) -> rfft -> transpose(v) -> rfft ->
//           vf-transpose -> attn(MFMA, K/V direct from L2) -> irfft
// All matmul-shaped compute runs on mfma_f32_16x16x32_bf16 with a 3-product
// error-compensated hi/lo split (~2^-17 per product; below f32-FFT floor).
// attn v3: NO K/V LDS staging (each element read once per block -> L2 direct,
// coalesced: K rows y-contiguous, V via pre-transposed vfT rows e-contiguous).
// LDS holds only the score planes (conflict-free (x&15)<<2 XOR swizzle).
// Workspace: 4 regions x 8,421,376 floats = 134,742,016 bytes.

typedef __attribute__((ext_vector_type(8))) short bf16x8;
typedef __attribute__((ext_vector_type(4))) float f32x4;

union U8 { bf16x8 v; unsigned u[4]; };

__device__ __forceinline__ unsigned short f2b(float x) {  // f32 -> bf16 RNE
  unsigned u = __float_as_uint(x);
  return (unsigned short)((u + 0x7FFFu + ((u >> 16) & 1u)) >> 16);
}
__device__ __forceinline__ float b2f(unsigned short h) {
  return __uint_as_float(((unsigned)h) << 16);
}
__device__ __forceinline__ unsigned cvtpk_bf16(float lo, float hi) {
  unsigned r;  // dst.lo16 = bf16(lo), dst.hi16 = bf16(hi)
  asm("v_cvt_pk_bf16_f32 %0, %1, %2" : "=v"(r) : "v"(lo), "v"(hi));
  return r;
}

// ---------------- Stockham FFT core, N=1024, 256 threads ----------------
__device__ __forceinline__ void fft1024(float2* b0, float2* b1,
                                        const float2* twd, int tid) {
  float2* src = b0;
  float2* dst = b1;
#pragma unroll
  for (int st = 0; st < 10; ++st) {
    __syncthreads();
#pragma unroll
    for (int qq = 0; qq < 2; ++qq) {
      int bi = tid + qq * 256;          // butterfly index in [0,512)
      int m = 1 << st;
      int j = bi >> st;
      int jm = j << st;
      float2 c0 = src[bi];
      float2 c1 = src[bi + 512];
      float2 w = twd[jm];
      float2 sum, dif, tw;
      sum.x = c0.x + c1.x; sum.y = c0.y + c1.y;
      dif.x = c0.x - c1.x; dif.y = c0.y - c1.y;
      tw.x = dif.x * w.x - dif.y * w.y;
      tw.y = dif.x * w.y + dif.y * w.x;
      dst[bi + jm] = sum;
      dst[bi + jm + m] = tw;
    }
    float2* tmp = src; src = dst; dst = tmp;
  }
  __syncthreads();
}

// ---------------- transpose: f32 [B][1024][512] -> f32 [B][512][1024] ---
__global__ __launch_bounds__(256) void transpose_kernel(
    const float* __restrict__ in, float* __restrict__ out) {
  __shared__ float tile[32][33];
  int b = blockIdx.z;
  int s0 = blockIdx.x * 32;
  int c0 = blockIdx.y * 32;
  int tx = threadIdx.x & 31;
  int ty = threadIdx.x >> 5;            // 0..7
  const float* ip = in + (size_t)b * (1024 * 512);
  float* op = out + (size_t)b * (1024 * 512);
#pragma unroll
  for (int i = 0; i < 32; i += 8)
    tile[ty + i][tx] = ip[(size_t)(s0 + ty + i) * 512 + c0 + tx];
  __syncthreads();
#pragma unroll
  for (int i = 0; i < 32; i += 8)
    op[(size_t)(c0 + ty + i) * 1024 + s0 + tx] = tile[tx][ty + i];
}

// ------- q split-transpose: f32 [B][1024 l][512 c] -> bf16-split pair ---
__global__ __launch_bounds__(256) void transpose_q_split(
    const float* __restrict__ in, unsigned* __restrict__ XPhi,
    unsigned* __restrict__ XPlo) {
  __shared__ float tile[32][33];
  int b = blockIdx.z;
  int l0 = blockIdx.x * 32;
  int c0 = blockIdx.y * 32;
  int tx = threadIdx.x & 31;
  int ty = threadIdx.x >> 5;            // 0..7
  const float* ip = in + (size_t)b * (1024 * 512);
#pragma unroll
  for (int i = 0; i < 32; i += 8)
    tile[ty + i][tx] = ip[(size_t)(l0 + ty + i) * 512 + c0 + tx];
  __syncthreads();
  int p = threadIdx.x & 15;
  int lb = threadIdx.x >> 4;            // 0..15
#pragma unroll
  for (int i = 0; i < 2; ++i) {
    int ll = lb + i * 16;
    float v0 = tile[ll][2 * p];
    float v1 = tile[ll][2 * p + 1];
    unsigned short h0 = f2b(v0), h1 = f2b(v1);
    unsigned short q0 = f2b(v0 - b2f(h0)), q1 = f2b(v1 - b2f(h1));
    size_t o = ((size_t)b * 1024 + l0 + ll) * 256 + (c0 >> 1) + p;
    XPhi[o] = (unsigned)h0 | ((unsigned)h1 << 16);
    XPlo[o] = (unsigned)q0 | ((unsigned)q1 << 16);
  }
}

// ------- W split-repack: [1024 og][512 c][3 t] f32 ->
//         Wsp[(p*3+t)*1024 + og] uint2 {hi_pair, lo_pair}, p = c/2 -------
__global__ __launch_bounds__(256) void transpose_w_split(
    const float* __restrict__ Win, uint2* __restrict__ Wsp) {
  __shared__ float tile[32][49];        // [og][48 ct = 8 pairs x 3 t x 2]
  int og0 = blockIdx.x * 32;
  int ct0 = blockIdx.y * 48;
  int tid = threadIdx.x;
#pragma unroll
  for (int i = 0; i < 6; ++i) {
    int flat = tid + i * 256;
    int og = flat / 48, ct = flat % 48;
    tile[og][ct] = Win[(size_t)(og0 + og) * 1536 + ct0 + ct];
  }
  __syncthreads();
  int ogl = tid & 31;
  int s = tid >> 5;                     // 0..7
#pragma unroll
  for (int i = 0; i < 3; ++i) {
    int pt = s + i * 8;                 // 0..23
    int pl = pt / 3, t = pt % 3;
    float v0 = tile[ogl][pl * 6 + t];       // c = 2*(ct0/6 + pl)
    float v1 = tile[ogl][pl * 6 + 3 + t];   // c+1
    unsigned short h0 = f2b(v0), h1 = f2b(v1);
    unsigned short q0 = f2b(v0 - b2f(h0)), q1 = f2b(v1 - b2f(h1));
    Wsp[((size_t)(ct0 / 6 + pl) * 3 + t) * 1024 + og0 + ogl] =
        make_uint2((unsigned)h0 | ((unsigned)h1 << 16),
                   (unsigned)q0 | ((unsigned)q1 << 16));
  }
}

// ------- Conv1d(512->1024,k=3,pad=1) + GLU via MFMA -> q2 [B][512][L] ---
__global__ __launch_bounds__(256, 2) void conv_glu_mfma(
    const unsigned* __restrict__ XPhi, const unsigned* __restrict__ XPlo,
    const uint2* __restrict__ Wsp, const float* __restrict__ bias,
    float* __restrict__ q2t) {
  __shared__ unsigned Whi[3 * 64 * 18];
  __shared__ unsigned Wlo[3 * 64 * 18];

  int tid = threadIdx.x;
  int w = tid >> 6;                     // wave 0..3
  int lane = tid & 63;
  int grp = lane >> 4;                  // k-group 0..3
  int lid = lane & 15;

  unsigned v0 = blockIdx.x;             // 0..1023
  int xcd = (int)(v0 & 7u);
  int j = (int)(v0 >> 3);               // 0..127
  int b = xcd * 2 + (j >> 6);
  int rem = j & 63;
  int ca = (rem >> 2) * 32;             // GLU channel base
  int l0 = (rem & 3) * 256;             // l base

  const unsigned* xh = XPhi + (size_t)b * 1024 * 256;
  const unsigned* xl = XPlo + (size_t)b * 1024 * 256;

  f32x4 acc[4][4];
#pragma unroll
  for (int mi = 0; mi < 4; ++mi)
#pragma unroll
    for (int ni = 0; ni < 4; ++ni) acc[mi][ni] = {0.f, 0.f, 0.f, 0.f};

  for (int c0 = 0; c0 < 512; c0 += 32) {
    __syncthreads();
#pragma unroll
    for (int i = 0; i < 12; ++i) {
      int flat = tid + i * 256;
      int ogi = flat & 63;
      int r = flat >> 6;                // 0..47
      int t = r % 3, p = r / 3;
      int og = (ogi < 32) ? (ca + ogi) : (480 + ca + ogi);
      uint2 g = Wsp[((size_t)((c0 >> 1) + p) * 3 + t) * 1024 + og];
      Whi[(t * 64 + ogi) * 18 + p] = g.x;
      Wlo[(t * 64 + ogi) * 18 + p] = g.y;
    }
    __syncthreads();

#pragma unroll
    for (int t = 0; t < 3; ++t) {
      U8 Ah[4], Al[4];
#pragma unroll
      for (int mi = 0; mi < 4; ++mi) {
        int base = (t * 64 + mi * 16 + lid) * 18 + 4 * grp;
        uint2 h0 = *(const uint2*)&Whi[base];
        uint2 h1 = *(const uint2*)&Whi[base + 2];
        uint2 g0 = *(const uint2*)&Wlo[base];
        uint2 g1 = *(const uint2*)&Wlo[base + 2];
        Ah[mi].u[0] = h0.x; Ah[mi].u[1] = h0.y;
        Ah[mi].u[2] = h1.x; Ah[mi].u[3] = h1.y;
        Al[mi].u[0] = g0.x; Al[mi].u[1] = g0.y;
        Al[mi].u[2] = g1.x; Al[mi].u[3] = g1.y;
      }
      U8 Bh[4], Bl[4];
#pragma unroll
      for (int ni = 0; ni < 4; ++ni) {
        unsigned gl = (unsigned)(l0 + w * 64 + ni * 16 + lid + t - 1);
        uint4 dh = make_uint4(0, 0, 0, 0), dl = make_uint4(0, 0, 0, 0);
        if (gl < 1024u) {
          size_t off = (size_t)gl * 256 + (c0 >> 1) + 4 * grp;
          dh = *(const uint4*)(xh + off);
          dl = *(const uint4*)(xl + off);
        }
        Bh[ni].u[0] = dh.x; Bh[ni].u[1] = dh.y;
        Bh[ni].u[2] = dh.z; Bh[ni].u[3] = dh.w;
        Bl[ni].u[0] = dl.x; Bl[ni].u[1] = dl.y;
        Bl[ni].u[2] = dl.z; Bl[ni].u[3] = dl.w;
      }
#pragma unroll
      for (int mi = 0; mi < 4; ++mi)
#pragma unroll
        for (int ni = 0; ni < 4; ++ni) {
          acc[mi][ni] = __builtin_amdgcn_mfma_f32_16x16x32_bf16(
              Ah[mi].v, Bl[ni].v, acc[mi][ni], 0, 0, 0);
          acc[mi][ni] = __builtin_amdgcn_mfma_f32_16x16x32_bf16(
              Al[mi].v, Bh[ni].v, acc[mi][ni], 0, 0, 0);
          acc[mi][ni] = __builtin_amdgcn_mfma_f32_16x16x32_bf16(
              Ah[mi].v, Bh[ni].v, acc[mi][ni], 0, 0, 0);
        }
    }
  }

#pragma unroll
  for (int mi = 0; mi < 2; ++mi)
#pragma unroll
    for (int rr = 0; rr < 4; ++rr) {
      int row = mi * 16 + grp * 4 + rr;     // 0..31
      float ba = bias[ca + row];
      float bg = bias[512 + ca + row];
      float* orow =
          q2t + ((size_t)b * 512 + ca + row) * 1024 + l0 + w * 64 + lid;
#pragma unroll
      for (int ni = 0; ni < 4; ++ni) {
        float a = acc[mi][ni][rr] + ba;
        float g = acc[mi + 2][ni][rr] + bg;
        orow[ni * 16] = a / (1.f + __expf(-g));
      }
    }
}

// ------- Forward rfft: f32 row [1024] -> 513 bf16-split complex ---------
__global__ __launch_bounds__(256) void fft_fwd_kernel(
    const float* __restrict__ in, ushort4* __restrict__ out, float scale) {
  __shared__ float2 sb0[1024];
  __shared__ float2 sb1[1024];
  __shared__ float2 twd[512];
  int tid = threadIdx.x;
  size_t r = blockIdx.x;                // row = (b*8+h)*64 + e
  const float* ip = in + r * 1024;
#pragma unroll
  for (int i = 0; i < 4; ++i) {
    int idx = tid + i * 256;
    sb0[idx] = make_float2(ip[idx], 0.f);
  }
  for (int kk = tid; kk < 512; kk += 256) {
    float ang = -6.283185307179586f * (float)kk * (1.0f / 1024.0f);
    float sn, cs;
    __sincosf(ang, &sn, &cs);
    twd[kk] = make_float2(cs, sn);
  }
  fft1024(sb0, sb1, twd, tid);
  ushort4* op = out + r * 514;          // padded row stride
  for (int x = tid; x < 513; x += 256) {
    float2 v = sb0[x];
    float re = v.x * scale, im = v.y * scale;
    unsigned short rh = f2b(re), ih = f2b(im);
    unsigned short rl = f2b(re - b2f(rh)), il = f2b(im - b2f(ih));
    op[x] = make_ushort4(rh, ih, rl, il);
  }
  if (tid == 0) op[513] = make_ushort4(0, 0, 0, 0);
}

// ------- vf transpose: [bh][64 e][514 y] uint2 -> vfT [bh][514 y][64 e] --
__global__ __launch_bounds__(256) void vft_kernel(
    const uint2* __restrict__ vf, uint2* __restrict__ vfT) {
  __shared__ uint2 tile[64][65];
  int bh = blockIdx.y;
  int y0 = blockIdx.x * 64;
  int tid = threadIdx.x;
  const uint2* src = vf + (size_t)bh * 64 * 514;
  uint2* dst = vfT + (size_t)bh * 514 * 64;
#pragma unroll
  for (int i = 0; i < 16; ++i) {
    int flat = tid + i * 256;
    int e = flat >> 6, y = flat & 63;
    int gy = y0 + y;
    uint2 d = make_uint2(0, 0);
    if (gy < 514) d = src[(size_t)e * 514 + gy];
    tile[e][y] = d;
  }
  __syncthreads();
#pragma unroll
  for (int i = 0; i < 16; ++i) {
    int flat = tid + i * 256;
    int y = flat >> 6, e = flat & 63;
    int gy = y0 + y;
    if (gy < 514) dst[(size_t)gy * 64 + e] = tile[e][y];
  }
}

// ---------------- Fused frequency attention v3 (MFMA, L2-direct K/V) -----
// Grid 2176 = 128 bh x 17 x-tiles (32 x each), XCD-swizzled. LDS = score
// planes only (hi/lo, (x&15)<<2 dword XOR; conflict-free writes & b128
// reads). K read straight from kf (y-contiguous per quarter); V from vfT
// (e-contiguous per quarter). 2 barriers per y-tile.
template <bool TAIL>
__device__ __forceinline__ void attn_tile(
    int y0, const uint2* __restrict__ kb, const uint2* __restrict__ vb,
    const U8 (&Ah)[2][4], const U8 (&Al)[2][4],
    unsigned* Shi, unsigned* Slo, float* zacc, f32x4* ore, f32x4* oim,
    int w, int grp, int lid) {
  int yk = y0 + 16 * w + lid;           // GEMM1 column owned by this lane
  // ---- GEMM1 K loads (b64, coalesced per quarter) ----
  uint2 BK[4][4];
  bool kval = !TAIL || (yk < 514);
#pragma unroll
  for (int ks = 0; ks < 4; ++ks)
#pragma unroll
    for (int jp = 0; jp < 4; ++jp) {
      int e = ks * 16 + grp * 4 + jp;
      if (!TAIL) {
        BK[ks][jp] = kb[(size_t)e * 514 + yk];
      } else {
        uint2 d = make_uint2(0, 0);
        if (kval) d = kb[(size_t)e * 514 + yk];
        BK[ks][jp] = d;
      }
    }
  f32x4 cre[2] = {{0.f, 0.f, 0.f, 0.f}, {0.f, 0.f, 0.f, 0.f}};
  f32x4 cim[2] = {{0.f, 0.f, 0.f, 0.f}, {0.f, 0.f, 0.f, 0.f}};
#pragma unroll
  for (int ks = 0; ks < 4; ++ks) {
    U8 bhh, bll, bih, bil;
#pragma unroll
    for (int jp = 0; jp < 4; ++jp) {
      unsigned uh = BK[ks][jp].x, ul = BK[ks][jp].y;
      bhh.u[jp] = uh;                                  // (kr, ki)
      bll.u[jp] = ul;
      bih.u[jp] = ((uh >> 16) ^ 0x8000u) | (uh << 16); // (-ki, kr)
      bil.u[jp] = ((ul >> 16) ^ 0x8000u) | (ul << 16);
    }
#pragma unroll
    for (int mt = 0; mt < 2; ++mt) {
      cre[mt] = __builtin_amdgcn_mfma_f32_16x16x32_bf16(Ah[mt][ks].v, bhh.v, cre[mt], 0, 0, 0);
      cre[mt] = __builtin_amdgcn_mfma_f32_16x16x32_bf16(Al[mt][ks].v, bhh.v, cre[mt], 0, 0, 0);
      cre[mt] = __builtin_amdgcn_mfma_f32_16x16x32_bf16(Ah[mt][ks].v, bll.v, cre[mt], 0, 0, 0);
      cim[mt] = __builtin_amdgcn_mfma_f32_16x16x32_bf16(Ah[mt][ks].v, bih.v, cim[mt], 0, 0, 0);
      cim[mt] = __builtin_amdgcn_mfma_f32_16x16x32_bf16(Al[mt][ks].v, bih.v, cim[mt], 0, 0, 0);
      cim[mt] = __builtin_amdgcn_mfma_f32_16x16x32_bf16(Ah[mt][ks].v, bil.v, cim[mt], 0, 0, 0);
    }
  }
  // ---- gate + L1 partial + split scores to LDS ----
#pragma unroll
  for (int mt = 0; mt < 2; ++mt)
#pragma unroll
    for (int r = 0; r < 4; ++r) {
      float sre = cre[mt][r], sim = cim[mt][r];
      float m = sqrtf(sre * sre + sim * sim);
      float f = 1.f + 1.f / (1.f + __expf(-m));
      zacc[mt * 4 + r] += m * f;
      float wre = sre * f, wim = sim * f;
      unsigned dh = cvtpk_bf16(wre, wim);
      float rre = wre - __uint_as_float(dh << 16);
      float rim = wim - __uint_as_float(dh & 0xffff0000u);
      unsigned dl = cvtpk_bf16(rre, rim);
      int x = mt * 16 + grp * 4 + r;
      int idx = x * 64 + ((16 * w + lid) ^ ((x & 15) << 2));
      Shi[idx] = dh;
      Slo[idx] = dl;
    }
  __syncthreads();
  // ---- GEMM2: of[x][e] += sc * vf ----
#pragma unroll
  for (int ks = 0; ks < 4; ++ks) {
    uint2 BV[4];
#pragma unroll
    for (int jp = 0; jp < 4; ++jp) {
      int yv = y0 + ks * 16 + grp * 4 + jp;
      if (!TAIL) {
        BV[jp] = vb[(size_t)yv * 64 + 16 * w + lid];
      } else {
        uint2 d = make_uint2(0, 0);
        if (yv < 514) d = vb[(size_t)yv * 64 + 16 * w + lid];
        BV[jp] = d;
      }
    }
    U8 bvh, bvl, bvi, bvj;
#pragma unroll
    for (int jp = 0; jp < 4; ++jp) {
      unsigned uh = BV[jp].x, ul = BV[jp].y;
      bvh.u[jp] = uh ^ 0x80000000u;            // (vr, -vi)
      bvl.u[jp] = ul ^ 0x80000000u;
      bvi.u[jp] = (uh >> 16) | (uh << 16);     // (vi, vr)
      bvj.u[jp] = (ul >> 16) | (ul << 16);
    }
#pragma unroll
    for (int mt = 0; mt < 2; ++mt) {
      int sidx = (mt * 16 + lid) * 64 + ((ks * 16 + grp * 4) ^ (lid << 2));
      U8 a2h, a2l;
      a2h.v = *(const bf16x8*)&Shi[sidx];
      a2l.v = *(const bf16x8*)&Slo[sidx];
      ore[mt] = __builtin_amdgcn_mfma_f32_16x16x32_bf16(a2h.v, bvh.v, ore[mt], 0, 0, 0);
      ore[mt] = __builtin_amdgcn_mfma_f32_16x16x32_bf16(a2l.v, bvh.v, ore[mt], 0, 0, 0);
      ore[mt] = __builtin_amdgcn_mfma_f32_16x16x32_bf16(a2h.v, bvl.v, ore[mt], 0, 0, 0);
      oim[mt] = __builtin_amdgcn_mfma_f32_16x16x32_bf16(a2h.v, bvi.v, oim[mt], 0, 0, 0);
      oim[mt] = __builtin_amdgcn_mfma_f32_16x16x32_bf16(a2l.v, bvi.v, oim[mt], 0, 0, 0);
      oim[mt] = __builtin_amdgcn_mfma_f32_16x16x32_bf16(a2h.v, bvj.v, oim[mt], 0, 0, 0);
    }
  }
  __syncthreads();                      // before next tile's S overwrite
}

__global__ __launch_bounds__(256, 3) void attn_kernel(
    const uint2* __restrict__ qf, const uint2* __restrict__ kf,
    const uint2* __restrict__ vfT, float2* __restrict__ of) {
  __shared__ __align__(16) unsigned char smem[16896];
  unsigned* Shi = (unsigned*)smem;              // [32 x][64 y] dw, swizzled
  unsigned* Slo = (unsigned*)(smem + 8192);
  float* zred = (float*)(smem + 16384);         // [4 w][32 x]

  int tid = threadIdx.x;
  int w = tid >> 6;                             // wave 0..3
  int lane = tid & 63;
  int grp = lane >> 4;                          // k-group 0..3
  int lid = lane & 15;

  unsigned v0 = blockIdx.x;                     // 0..2175
  unsigned cc = v0 & 7u;                        // XCD
  unsigned jj = v0 >> 3;                        // 0..271
  int bh = (int)(cc + 8u * (jj / 17u));
  int x0 = (int)(jj % 17u) * 32;

  const uint2* qb = qf + (size_t)bh * (64 * 514);
  const uint2* kb = kf + (size_t)bh * (64 * 514);
  const uint2* vb = vfT + (size_t)bh * (514 * 64);

  // ---- A fragments (q) direct from global (coalesced per quarter) ----
  U8 Ah[2][4], Al[2][4];
#pragma unroll
  for (int mt = 0; mt < 2; ++mt) {
    int gx = x0 + mt * 16 + lid;
    bool qv = gx < 514;
#pragma unroll
    for (int ks = 0; ks < 4; ++ks)
#pragma unroll
      for (int jp = 0; jp < 4; ++jp) {
        int e = ks * 16 + grp * 4 + jp;
        uint2 d = make_uint2(0, 0);
        if (qv) d = qb[(size_t)e * 514 + gx];
        Ah[mt][ks].u[jp] = d.x;
        Al[mt][ks].u[jp] = d.y;
      }
  }

  float zacc[8] = {0.f, 0.f, 0.f, 0.f, 0.f, 0.f, 0.f, 0.f};
  f32x4 ore[2] = {{0.f, 0.f, 0.f, 0.f}, {0.f, 0.f, 0.f, 0.f}};
  f32x4 oim[2] = {{0.f, 0.f, 0.f, 0.f}, {0.f, 0.f, 0.f, 0.f}};

#pragma unroll 1
  for (int yt = 0; yt < 8; ++yt)
    attn_tile<false>(yt * 64, kb, vb, Ah, Al, Shi, Slo, zacc, ore, oim,
                     w, grp, lid);
  attn_tile<true>(512, kb, vb, Ah, Al, Shi, Slo, zacc, ore, oim,
                  w, grp, lid);

  // ---- Z reduction: per-lane partials -> per-x totals ----
#pragma unroll
  for (int mt = 0; mt < 2; ++mt)
#pragma unroll
    for (int r = 0; r < 4; ++r) {
      float z = zacc[mt * 4 + r];
      z += __shfl_xor(z, 1); z += __shfl_xor(z, 2);
      z += __shfl_xor(z, 4); z += __shfl_xor(z, 8);
      zacc[mt * 4 + r] = z;
    }
  if (lid == 0) {
#pragma unroll
    for (int mt = 0; mt < 2; ++mt)
#pragma unroll
      for (int r = 0; r < 4; ++r)
        zred[w * 32 + mt * 16 + grp * 4 + r] = zacc[mt * 4 + r];
  }
  __syncthreads();
  // ---- normalize + stage output tile [64 e][32 x] (swz x ^ ((e&7)<<2)) ----
  float2* ov = (float2*)smem;           // aliases S planes (16 KB)
#pragma unroll
  for (int mt = 0; mt < 2; ++mt)
#pragma unroll
    for (int r = 0; r < 4; ++r) {
      int x = mt * 16 + grp * 4 + r;
      float z = zred[x] + zred[32 + x] + zred[64 + x] + zred[96 + x];
      float inv = 1.f / fmaxf(z, 1e-12f);
      int e = w * 16 + lid;
      ov[e * 32 + (x ^ ((e & 7) << 2))] =
          make_float2(ore[mt][r] * inv, oim[mt][r] * inv);
    }
  __syncthreads();
  // ---- coalesced write: of[(bh*64+e)*513 + x] ----
  {
    float2* ob = of + (size_t)bh * 64 * 513;
#pragma unroll
    for (int i = 0; i < 4; ++i) {
      int e = (tid >> 4) + i * 16;
      int xq = (tid & 15) * 2;
      int sw = (e & 7) << 2;
      float2 a = ov[e * 32 + (xq ^ sw)];
      float2 b2 = ov[e * 32 + ((xq + 1) ^ sw)];
      int gx = x0 + xq;
      if (gx < 513) ob[(size_t)e * 513 + gx] = a;
      if (gx + 1 < 513) ob[(size_t)e * 513 + gx + 1] = b2;
    }
  }
}

// ------- Inverse rfft (ortho), of stride 513 -> f32 out [B,L,H,E] -------
__global__ __launch_bounds__(256) void fft_inv_kernel(
    const float2* __restrict__ in, float* __restrict__ out) {
  __shared__ float2 sb0[1024];
  __shared__ float2 sb1[1024];
  __shared__ float2 twd[512];
  int tid = threadIdx.x;
  size_t r = blockIdx.x;                // (b*8+h)*64 + e
  const float2* ip = in + r * 513;
#pragma unroll
  for (int i = 0; i < 4; ++i) {
    int idx = tid + i * 256;
    float2 v;
    if (idx < 513) {
      v = ip[idx];
    } else {                            // Hermitian mirror
      float2 u = ip[1024 - idx];
      v = make_float2(u.x, -u.y);
    }
    sb0[idx] = v;
  }
  for (int kk = tid; kk < 512; kk += 256) {
    float ang = 6.283185307179586f * (float)kk * (1.0f / 1024.0f);
    float sn, cs;
    __sincosf(ang, &sn, &cs);
    twd[kk] = make_float2(cs, sn);
  }
  fft1024(sb0, sb1, twd, tid);
  int e = (int)(r & 63);
  int h = (int)((r >> 6) & 7);
  size_t b = r >> 9;
  float* op = out + b * (size_t)(1024 * 512) + (size_t)h * 64 + e;
  const float sc = 0.03125f;            // 1/sqrt(1024)
#pragma unroll
  for (int i = 0; i < 4; ++i) {
    int l = tid + i * 256;
    op[(size_t)l * 512] = sb0[l].x * sc;
  }
}

// ---------------- launch ------------------------------------------------
extern "C" void kernel_launch(void* const* d_in, const int* in_sizes, int n_in,
                              void* d_out, int out_size, void* d_ws, size_t ws_size,
                              hipStream_t stream) {
  const float* q = (const float*)d_in[0];
  const float* k = (const float*)d_in[1];
  const float* v = (const float*)d_in[2];
  const float* W = (const float*)d_in[3];
  const float* bias = (const float*)d_in[4];
  float* out = (float*)d_out;

  // Workspace map (float offsets), regions of 8,421,376 floats each:
  //   A   [0)         reused: q2t -> kT -> vT -> vfT
  //   QFR [8421376)   reused: XPhi+XPlo (split q) -> qf (bf16-split freq)
  //   R2  [16842752)  reused: Wsp (split W) -> vf -> of
  //   R3  [25264128)  kf
  float* wsf = (float*)d_ws;
  float*    A    = wsf;
  uint2*    vfT  = (uint2*)wsf;
  unsigned* XPhi = (unsigned*)(wsf + 8421376);
  unsigned* XPlo = XPhi + (size_t)16 * 1024 * 256;   // +16 MB
  ushort4*  qf   = (ushort4*)(wsf + 8421376);
  uint2*    Wsp  = (uint2*)(wsf + 16842752);
  ushort4*  vf   = (ushort4*)(wsf + 16842752);
  float2*   of   = (float2*)(wsf + 16842752);        // overwrites vf
  ushort4*  kf   = (ushort4*)(wsf + 25264128);

  transpose_q_split<<<dim3(32, 16, 16), 256, 0, stream>>>(q, XPhi, XPlo);
  transpose_w_split<<<dim3(32, 32), 256, 0, stream>>>(W, Wsp);
  conv_glu_mfma<<<dim3(1024), 256, 0, stream>>>(XPhi, XPlo, Wsp, bias, A);
  fft_fwd_kernel<<<dim3(8192), 256, 0, stream>>>(A, qf, 0.03125f * 0.125f);
  transpose_kernel<<<dim3(32, 16, 16), 256, 0, stream>>>(k, A);
  fft_fwd_kernel<<<dim3(8192), 256, 0, stream>>>(A, kf, 0.03125f);
  transpose_kernel<<<dim3(32, 16, 16), 256, 0, stream>>>(v, A);
  fft_fwd_kernel<<<dim3(8192), 256, 0, stream>>>(A, vf, 0.03125f);
  vft_kernel<<<dim3(9, 128), 256, 0, stream>>>((const uint2*)vf, vfT);
  attn_kernel<<<dim3(2176), 256, 0, stream>>>((const uint2*)qf, (const uint2*)kf,
                                              vfT, of);
  fft_inv_kernel<<<dim3(8192), 256, 0, stream>>>(of, out);
}